// Round 1
// baseline (742.424 us; speedup 1.0000x reference)
//
#include <hip/hip_runtime.h>
#include <hip/hip_bf16.h>
#include <math.h>

typedef __bf16 bf16;
typedef __bf16 bf16x4 __attribute__((ext_vector_type(4)));
typedef __bf16 bf16x8 __attribute__((ext_vector_type(8)));
typedef float  floatx4 __attribute__((ext_vector_type(4)));

#define N_TOK 8192   // B*S
#define E_DIM 1024
#define G_DIM 8
#define O_DIM 4096
#define EPI_LD 132   // padded leading dim of epilogue LDS tile (bf16) for old gemm

__device__ __forceinline__ void gload_lds16(const void* g, void* l) {
    __builtin_amdgcn_global_load_lds(
        (__attribute__((address_space(1))) void*)(g),
        (__attribute__((address_space(3))) void*)(l),
        16, 0, 0);
}

// ---------------------------------------------------------------------------
// 1) gate = X @ WG; top-2. NO atomics: writes per-entry expert id + scale.
// ---------------------------------------------------------------------------
__global__ __launch_bounds__(256) void gate_compute(
    const float* __restrict__ X,   // [N_TOK][E_DIM]
    const float* __restrict__ WG,  // [E_DIM][G_DIM]
    int* __restrict__ sel,         // [N_TOK*2] expert id
    float* __restrict__ sval)      // [N_TOK*2] sigmoid-0.5
{
    __shared__ float lwgT[G_DIM * E_DIM];   // [g][e], 32 KB
    const int tid  = threadIdx.x;
    const int wave = tid >> 6;
    const int lane = tid & 63;

#pragma unroll
    for (int k = 0; k < 8; ++k) {
        const int i = k * 256 + tid;
        const float4 v = *(const float4*)(WG + i * 4);
        const int e  = i >> 1;
        const int g0 = (i & 1) * 4;
        lwgT[(g0 + 0) * E_DIM + e] = v.x;
        lwgT[(g0 + 1) * E_DIM + e] = v.y;
        lwgT[(g0 + 2) * E_DIM + e] = v.z;
        lwgT[(g0 + 3) * E_DIM + e] = v.w;
    }
    __syncthreads();

    const int t = blockIdx.x * 4 + wave;
    float acc[G_DIM];
#pragma unroll
    for (int g = 0; g < G_DIM; ++g) acc[g] = 0.f;

#pragma unroll
    for (int it = 0; it < 4; ++it) {
        const int e0 = it * 256 + lane * 4;
        const float4 xv = *(const float4*)(X + (long)t * E_DIM + e0);
#pragma unroll
        for (int g = 0; g < G_DIM; ++g) {
            const float4 wv = *(const float4*)(lwgT + g * E_DIM + e0);
            acc[g] += xv.x * wv.x + xv.y * wv.y + xv.z * wv.z + xv.w * wv.w;
        }
    }
#pragma unroll
    for (int g = 0; g < G_DIM; ++g) {
        float v = acc[g];
#pragma unroll
        for (int off = 32; off > 0; off >>= 1) v += __shfl_down(v, off, 64);
        acc[g] = v;  // valid on lane 0
    }
    if (lane == 0) {
        int i1 = 0;
#pragma unroll
        for (int g = 1; g < G_DIM; ++g) if (acc[g] > acc[i1]) i1 = g;
        int i2 = (i1 == 0) ? 1 : 0;
#pragma unroll
        for (int g = 0; g < G_DIM; ++g)
            if (g != i1 && g != i2 && acc[g] > acc[i2]) i2 = g;
#pragma unroll
        for (int s = 0; s < 2; ++s) {
            const int g = s ? i2 : i1;
            sel[t * 2 + s]  = g;
            sval[t * 2 + s] = 1.f / (1.f + expf(-acc[g])) - 0.5f;
        }
    }
}

// ---------------------------------------------------------------------------
// 1b) routing: ballot histogram + prefix + stable scatter. 1 block x 1024.
// ---------------------------------------------------------------------------
__global__ __launch_bounds__(1024) void route_kernel(
    const int* __restrict__ sel, const float* __restrict__ sval,
    int* __restrict__ cnt, int* __restrict__ off, int* __restrict__ offp,
    int* __restrict__ tok, float* __restrict__ scl, int* __restrict__ pos)
{
    __shared__ int hcnt[16][G_DIM];
    __shared__ int wbase[16][G_DIM];
    const int tid  = threadIdx.x;
    const int w    = tid >> 6;
    const int lane = tid & 63;
    const unsigned long long below = ((unsigned long long)1 << lane) - 1;

    int c0[G_DIM];
#pragma unroll
    for (int g = 0; g < G_DIM; ++g) c0[g] = 0;
    for (int c = 0; c < 16; ++c) {
        const int g = sel[w * 1024 + c * 64 + lane];
#pragma unroll
        for (int gg = 0; gg < G_DIM; ++gg)
            c0[gg] += __popcll(__ballot(g == gg));
    }
    if (lane == 0)
#pragma unroll
        for (int g = 0; g < G_DIM; ++g) hcnt[w][g] = c0[g];
    __syncthreads();

    if (tid == 0) {
        int tot[G_DIM];
#pragma unroll
        for (int g = 0; g < G_DIM; ++g) {
            int a = 0;
            for (int ww = 0; ww < 16; ++ww) { wbase[ww][g] = a; a += hcnt[ww][g]; }
            tot[g] = a; cnt[g] = a;
        }
        int a = 0, b = 0;
#pragma unroll
        for (int g = 0; g < G_DIM; ++g) {
            off[g]  = a; a += tot[g];
            offp[g] = b; b += (tot[g] + 127) & ~127;
        }
        offp[G_DIM] = b;
    }
    __syncthreads();

    int run[G_DIM];
#pragma unroll
    for (int g = 0; g < G_DIM; ++g) run[g] = 0;
    for (int c = 0; c < 16; ++c) {
        const int idx = w * 1024 + c * 64 + lane;
        const int g   = sel[idx];
        const float sv = sval[idx];
        int myrank = 0;
#pragma unroll
        for (int gg = 0; gg < G_DIM; ++gg) {
            const unsigned long long m = __ballot(g == gg);
            const int r = run[gg] + __popcll(m & below);
            if (g == gg) myrank = r;
            run[gg] += __popcll(m);
        }
        const int p = wbase[w][g] + myrank;
        tok[g * N_TOK + p] = idx >> 1;
        scl[g * N_TOK + p] = sv;
        pos[idx] = (g << 16) | p;
    }
}

// ---------------------------------------------------------------------------
// 2) X fp32 -> bf16
// ---------------------------------------------------------------------------
__global__ __launch_bounds__(256) void convert_x(
    const float* __restrict__ X, bf16* __restrict__ Xb)
{
    const long i = ((long)blockIdx.x * 256 + threadIdx.x) * 4;
    const float4 v = *(const float4*)(X + i);
    bf16x4 o;
    o[0] = (bf16)v.x; o[1] = (bf16)v.y; o[2] = (bf16)v.z; o[3] = (bf16)v.w;
    *(bf16x4*)(Xb + i) = o;
}

// ---------------------------------------------------------------------------
// 3) transpose + fp32->bf16: S[R][C] -> D[C][R]
// ---------------------------------------------------------------------------
__global__ __launch_bounds__(256) void transpose_conv(
    const float* __restrict__ S, bf16* __restrict__ D, int R, int C)
{
    __shared__ float tile[64][65];
    const int r0  = blockIdx.x * 64;
    const int c0  = blockIdx.y * 64;
    const int tid = threadIdx.x;
    const int tr  = tid >> 4;          // 0..15
    const int tc4 = (tid & 15) * 4;    // 0..60

#pragma unroll
    for (int p = 0; p < 4; ++p) {
        const int r = p * 16 + tr;
        const float4 v = *(const float4*)(S + (long)(r0 + r) * C + c0 + tc4);
        tile[r][tc4 + 0] = v.x;
        tile[r][tc4 + 1] = v.y;
        tile[r][tc4 + 2] = v.z;
        tile[r][tc4 + 3] = v.w;
    }
    __syncthreads();
#pragma unroll
    for (int p = 0; p < 4; ++p) {
        const int c = p * 16 + tr;     // source col == dest row
        bf16x4 o;
        o[0] = (bf16)tile[tc4 + 0][c];
        o[1] = (bf16)tile[tc4 + 1][c];
        o[2] = (bf16)tile[tc4 + 2][c];
        o[3] = (bf16)tile[tc4 + 3][c];
        *(bf16x4*)(D + (long)(c0 + c) * R + r0 + tc4) = o;
    }
}

// ---------------------------------------------------------------------------
// 4) WsumT[o][e] = 0.5 * sum_g WiT[o][g*1024+e]   (bf16)
// ---------------------------------------------------------------------------
__global__ __launch_bounds__(256) void wsum_kernel(
    const bf16* __restrict__ WiT, bf16* __restrict__ WsumT)
{
    const int o  = blockIdx.x;
    const int e4 = threadIdx.x * 4;
    float a0 = 0.f, a1 = 0.f, a2 = 0.f, a3 = 0.f;
#pragma unroll
    for (int g = 0; g < G_DIM; ++g) {
        const bf16x4 v = *(const bf16x4*)(WiT + (long)o * 8192 + g * E_DIM + e4);
        a0 += (float)v[0]; a1 += (float)v[1]; a2 += (float)v[2]; a3 += (float)v[3];
    }
    bf16x4 w;
    w[0] = (bf16)(0.5f * a0); w[1] = (bf16)(0.5f * a1);
    w[2] = (bf16)(0.5f * a2); w[3] = (bf16)(0.5f * a3);
    *(bf16x4*)(WsumT + (long)o * E_DIM + e4) = w;
}

// ---------------------------------------------------------------------------
// 5) gather rows of Xb into expert-sorted, 128-padded Xs. One block per slot.
// ---------------------------------------------------------------------------
__global__ __launch_bounds__(128) void gather_rows(
    const bf16* __restrict__ Xb, const int* __restrict__ cnt,
    const int* __restrict__ offp, const int* __restrict__ tok,
    bf16* __restrict__ Xs)
{
    const int slot = blockIdx.x;
    if (slot >= offp[G_DIM]) return;
    int g = 0;
    while (slot >= offp[g + 1]) ++g;
    const int p = slot - offp[g];
    bf16* dst = Xs + (long)slot * E_DIM + threadIdx.x * 8;
    if (p < cnt[g]) {
        const bf16* src = Xb + (long)tok[g * N_TOK + p] * E_DIM + threadIdx.x * 8;
        *(bf16x8*)dst = *(const bf16x8*)src;
    } else {
        bf16x8 z = {};
        *(bf16x8*)dst = z;
    }
}

// ---------------------------------------------------------------------------
// 6) 256x256 / BK=64 / 8-wave GEMM core (T2 swizzle + T3/T4 counted vmcnt +
//    T5 setprio).  A [.][lda], BT [.][ldb] row-major bf16, pre-offset to the
//    tile origin.  LDS: 2 buffers x (A 32KB + B 32KB) = 128 KiB.
//    Swizzle: within each 128B LDS row, byte ^= ((row&7)<<4); applied on the
//    GLOBAL source address at staging (global_load_lds dest is linear) and on
//    the ds_read address (both-sides involution).
// ---------------------------------------------------------------------------
__device__ __forceinline__ void gemm_core256(
    const bf16* __restrict__ Ap, long lda,
    const bf16* __restrict__ Bp, long ldb,
    int K, char* smem, floatx4 (&acc)[8][4])
{
    const int tid  = threadIdx.x;
    const int wave = tid >> 6;
    const int lane = tid & 63;
    const int wm   = wave >> 2;     // 0..1  (wave row)
    const int wn   = wave & 3;      // 0..3  (wave col)
    const int fr   = lane & 15;
    const int fq   = lane >> 4;

#pragma unroll
    for (int i = 0; i < 8; ++i)
#pragma unroll
        for (int j = 0; j < 4; ++j)
            acc[i][j] = (floatx4){0.f, 0.f, 0.f, 0.f};

    // staging: per call, 512 threads x 16B = 64 rows of 128B. Thread covers
    // (row = srow, colB = (tid&7)*16); source column pre-swizzled.
    const int  srow = tid >> 3;                         // 0..63
    const int  ssw  = ((tid & 7) * 16) ^ ((srow & 7) << 4);
    const char* sa  = (const char*)Ap + (long)srow * (lda * 2) + ssw;
    const char* sb  = (const char*)Bp + (long)srow * (ldb * 2) + ssw;
    const long a64  = lda * 128;    // 64 rows, bytes
    const long b64  = ldb * 128;
    char* const lw  = smem + wave * 1024;   // wave-uniform LDS slice base

#define STAGE256(buf, kt) do {                                              \
        const long _ko = (long)(kt) * 128;                                  \
        char* _lb = lw + (buf) * 65536;                                     \
        _Pragma("unroll")                                                   \
        for (int _c = 0; _c < 4; ++_c) {                                    \
            gload_lds16(sa + _ko + _c * a64, _lb + _c * 8192);              \
            gload_lds16(sb + _ko + _c * b64, _lb + 32768 + _c * 8192);      \
        }                                                                   \
    } while (0)

    // ds_read offsets (swizzled): logical (row, kbyte) -> row*128 + (kbyte^xsw)
    const int xsw  = (fr & 7) << 4;
    const int ko0  = (fq * 16) ^ xsw;          // k-sub 0
    const int ko1  = (fq * 16 + 64) ^ xsw;     // k-sub 1
    const int aoff = (wm * 128 + fr) * 128;            // A region
    const int boff = 32768 + (wn * 64 + fr) * 128;     // B region

    const int nt = K >> 6;
    STAGE256(0, 0);
    STAGE256(1, 1);
    asm volatile("s_waitcnt vmcnt(8)" ::: "memory");
    __builtin_amdgcn_s_barrier();
    __builtin_amdgcn_sched_barrier(0);

    bf16x8 af[4][2], bv[2][2];

    for (int t = 0; t < nt; ++t) {
        const char* base = smem + ((t & 1) << 16);

        // ---- phase 1: quadrant (mh=0, nh=0) ----
#pragma unroll
        for (int i = 0; i < 4; ++i) {
            af[i][0] = *(const bf16x8*)(base + aoff + i * 2048 + ko0);
            af[i][1] = *(const bf16x8*)(base + aoff + i * 2048 + ko1);
        }
#pragma unroll
        for (int j = 0; j < 2; ++j) {
            bv[j][0] = *(const bf16x8*)(base + boff + j * 2048 + ko0);
            bv[j][1] = *(const bf16x8*)(base + boff + j * 2048 + ko1);
        }
        __builtin_amdgcn_s_setprio(1);
#pragma unroll
        for (int i = 0; i < 4; ++i)
#pragma unroll
            for (int j = 0; j < 2; ++j) {
                acc[i][j] = __builtin_amdgcn_mfma_f32_16x16x32_bf16(af[i][0], bv[j][0], acc[i][j], 0, 0, 0);
                acc[i][j] = __builtin_amdgcn_mfma_f32_16x16x32_bf16(af[i][1], bv[j][1], acc[i][j], 0, 0, 0);
            }
        __builtin_amdgcn_s_setprio(0);

        // ---- phase 2: quadrant (0,1): new B ----
#pragma unroll
        for (int j = 0; j < 2; ++j) {
            bv[j][0] = *(const bf16x8*)(base + boff + 4096 + j * 2048 + ko0);
            bv[j][1] = *(const bf16x8*)(base + boff + 4096 + j * 2048 + ko1);
        }
        __builtin_amdgcn_s_setprio(1);
#pragma unroll
        for (int i = 0; i < 4; ++i)
#pragma unroll
            for (int j = 0; j < 2; ++j) {
                acc[i][2 + j] = __builtin_amdgcn_mfma_f32_16x16x32_bf16(af[i][0], bv[j][0], acc[i][2 + j], 0, 0, 0);
                acc[i][2 + j] = __builtin_amdgcn_mfma_f32_16x16x32_bf16(af[i][1], bv[j][1], acc[i][2 + j], 0, 0, 0);
            }
        __builtin_amdgcn_s_setprio(0);

        // ---- phase 3: quadrant (1,1): new A ----
#pragma unroll
        for (int i = 0; i < 4; ++i) {
            af[i][0] = *(const bf16x8*)(base + aoff + 8192 + i * 2048 + ko0);
            af[i][1] = *(const bf16x8*)(base + aoff + 8192 + i * 2048 + ko1);
        }
        __builtin_amdgcn_s_setprio(1);
#pragma unroll
        for (int i = 0; i < 4; ++i)
#pragma unroll
            for (int j = 0; j < 2; ++j) {
                acc[4 + i][2 + j] = __builtin_amdgcn_mfma_f32_16x16x32_bf16(af[i][0], bv[j][0], acc[4 + i][2 + j], 0, 0, 0);
                acc[4 + i][2 + j] = __builtin_amdgcn_mfma_f32_16x16x32_bf16(af[i][1], bv[j][1], acc[4 + i][2 + j], 0, 0, 0);
            }
        __builtin_amdgcn_s_setprio(0);

        // ---- phase 4: quadrant (1,0): new B ----
#pragma unroll
        for (int j = 0; j < 2; ++j) {
            bv[j][0] = *(const bf16x8*)(base + boff + j * 2048 + ko0);
            bv[j][1] = *(const bf16x8*)(base + boff + j * 2048 + ko1);
        }
        __builtin_amdgcn_s_setprio(1);
#pragma unroll
        for (int i = 0; i < 4; ++i)
#pragma unroll
            for (int j = 0; j < 2; ++j) {
                acc[4 + i][j] = __builtin_amdgcn_mfma_f32_16x16x32_bf16(af[i][0], bv[j][0], acc[4 + i][j], 0, 0, 0);
                acc[4 + i][j] = __builtin_amdgcn_mfma_f32_16x16x32_bf16(af[i][1], bv[j][1], acc[4 + i][j], 0, 0, 0);
            }
        __builtin_amdgcn_s_setprio(0);

        // ---- tile boundary: all waves done reading buf[t&1] ----
        __builtin_amdgcn_sched_barrier(0);
        __builtin_amdgcn_s_barrier();
        if (t + 2 < nt) {
            STAGE256(t & 1, t + 2);                        // refill the buffer just consumed
            asm volatile("s_waitcnt vmcnt(8)" ::: "memory"); // tile t+1 fully landed
        } else {
            asm volatile("s_waitcnt vmcnt(0)" ::: "memory"); // tail drain
        }
        __builtin_amdgcn_s_barrier();
        __builtin_amdgcn_sched_barrier(0);
    }
#undef STAGE256
}

// ---------------------------------------------------------------------------
// 6a) base GEMM: Yb = Xb @ WsumT^T  (bf16 out), M=8192 N=4096 K=1024.
//     grid 512 = 32 mtiles x 16 coltiles; same-B-panel blocks on one XCD.
// ---------------------------------------------------------------------------
__global__ __launch_bounds__(512, 2) void gemm256_base(
    const bf16* __restrict__ A, const bf16* __restrict__ BT,
    bf16* __restrict__ C)
{
    __shared__ __align__(16) char smem[131072];
    const int u   = blockIdx.x;
    const int xcd = u & 7;
    const int s   = u >> 3;
    const int mt  = s & 31;
    const int ct  = xcd + 8 * (s >> 5);
    const int row0 = mt * 256, col0 = ct * 256;

    floatx4 acc[8][4];
    gemm_core256(A + (long)row0 * E_DIM, E_DIM,
                 BT + (long)col0 * E_DIM, E_DIM,
                 E_DIM, smem, acc);

    const int tid = threadIdx.x, wave = tid >> 6, lane = tid & 63;
    const int wm = wave >> 2, wn = wave & 3, fr = lane & 15, fq = lane >> 4;
    bf16* tile = (bf16*)smem;
#pragma unroll
    for (int i = 0; i < 8; ++i)
#pragma unroll
        for (int j = 0; j < 4; ++j)
#pragma unroll
            for (int r = 0; r < 4; ++r)
                tile[(wm * 128 + i * 16 + fq * 4 + r) * 256 + wn * 64 + j * 16 + fr] =
                    (bf16)(acc[i][j][r]);
    __syncthreads();
#pragma unroll
    for (int k = 0; k < 16; ++k) {
        const int rl = (tid >> 5) + k * 16;
        const int cc = (tid & 31) * 8;
        *(bf16x8*)(C + (long)(row0 + rl) * O_DIM + col0 + cc) =
            *(const bf16x8*)(tile + rl * 256 + cc);
    }
}

// ---------------------------------------------------------------------------
// 6b) sparse grouped GEMM on sorted A (256x256 tiles). Tiles may straddle an
//     expert's 128-padded boundary: straddling rows compute garbage that the
//     store mask drops (MFMA rows are independent). End-of-Xs slack reads land
//     in the allocated Yb region (finite bf16).
//     grid 8192 = 8 experts x 64 mtiles x 16 coltiles, expert g pinned to XCD g.
// ---------------------------------------------------------------------------
__global__ __launch_bounds__(512, 2) void gemm256_sparse(
    const bf16* __restrict__ Xs,   // [padded slots][E_DIM]
    const bf16* __restrict__ WiT,  // [O_DIM][8192]
    const int* __restrict__ cnt,
    const int* __restrict__ off,
    const int* __restrict__ offp,
    const float* __restrict__ scl,
    bf16* __restrict__ ysp)        // [2*N_TOK][O_DIM] compact
{
    const int u   = blockIdx.x;
    const int xcd = u & 7;
    const int s   = u >> 3;
    const int mt  = s & 63;
    const int pc  = xcd + 8 * (s >> 6);   // [0,128)
    const int g   = pc & 7;
    const int ct  = pc >> 3;              // [0,16)

    const int cg     = cnt[g];
    const int base_p = offp[g];
    const int cgp    = offp[g + 1] - base_p;
    const int m0     = mt * 256;
    if (m0 >= cgp) return;

    __shared__ __align__(16) char smem[131072];
    const int col0 = ct * 256;

    floatx4 acc[8][4];
    gemm_core256(Xs + (long)(base_p + m0) * E_DIM, E_DIM,
                 WiT + (long)col0 * 8192 + g * E_DIM, 8192,
                 E_DIM, smem, acc);

    const int tid = threadIdx.x, wave = tid >> 6, lane = tid & 63;
    const int wm = wave >> 2, wn = wave & 3, fr = lane & 15, fq = lane >> 4;
    const float* sclg = scl + g * N_TOK;
    const int clmax = cg - 1;
    bf16* tile = (bf16*)smem;
#pragma unroll
    for (int i = 0; i < 8; ++i)
#pragma unroll
        for (int r = 0; r < 4; ++r) {
            const int rl = wm * 128 + i * 16 + fq * 4 + r;
            const int gm = m0 + rl;
            const float sv = sclg[gm > clmax ? clmax : gm];
#pragma unroll
            for (int j = 0; j < 4; ++j)
                tile[rl * 256 + wn * 64 + j * 16 + fr] = (bf16)(sv * acc[i][j][r]);
        }
    __syncthreads();
    const long ob = off[g] + m0;
#pragma unroll
    for (int k = 0; k < 16; ++k) {
        const int rl = (tid >> 5) + k * 16;
        if (m0 + rl < cg) {
            const int cc = (tid & 31) * 8;
            *(bf16x8*)(ysp + (ob + rl) * O_DIM + col0 + cc) =
                *(const bf16x8*)(tile + rl * 256 + cc);
        }
    }
}

// ---------------------------------------------------------------------------
// 6c) legacy 128x128 dense GEMM (kept for the down projection: N=1024 would
//     give only 128 blocks at 256x256).
// ---------------------------------------------------------------------------
template <typename OUT, bool VEC>
__global__ __launch_bounds__(256, 4) void gemm_mt(
    const bf16* __restrict__ A, int lda,
    const bf16* __restrict__ BT, int ldb,
    OUT* __restrict__ C, int ldc, int K)
{
    __shared__ char smem[VEC ? (128 * EPI_LD * 2) : 16384];
    bf16* As = (bf16*)smem;
    bf16* Bs = (bf16*)(smem + 8192);

    const int u   = blockIdx.x;
    const int xcd = u & 7;
    const int s   = u >> 3;
    const int mt  = s & 63;
    const int col = xcd + 8 * (s >> 6);

    const int tid  = threadIdx.x;
    const int wave = tid >> 6;
    const int lane = tid & 63;
    const int row0 = mt * 128;
    const int col0 = col * 128;

    const int sr = lane >> 2;
    const int sc = (lane & 3) * 8;
    const bf16* agp0 = A  + (long)(row0 + 16 * wave       + sr) * lda + sc;
    const bf16* agp1 = A  + (long)(row0 + 16 * (wave + 4) + sr) * lda + sc;
    const bf16* bgp0 = BT + (long)(col0 + 16 * wave       + sr) * ldb + sc;
    const bf16* bgp1 = BT + (long)(col0 + 16 * (wave + 4) + sr) * ldb + sc;
    bf16* asl0 = As + (long)wave * 512;
    bf16* asl1 = As + (long)(wave + 4) * 512;
    bf16* bsl0 = Bs + (long)wave * 512;
    bf16* bsl1 = Bs + (long)(wave + 4) * 512;

    const int mi_base = (wave >> 1) * 64;
    const int ni_base = (wave & 1) * 64;
    const int fr = lane & 15;
    const int fq = lane >> 4;

    floatx4 acc[4][4] = {};

    for (int k0 = 0; k0 < K; k0 += 32) {
        __syncthreads();
        gload_lds16(agp0 + k0, (void*)asl0);
        gload_lds16(agp1 + k0, (void*)asl1);
        gload_lds16(bgp0 + k0, (void*)bsl0);
        gload_lds16(bgp1 + k0, (void*)bsl1);
        __syncthreads();

        bf16x8 af[4], bfr[4];
#pragma unroll
        for (int i = 0; i < 4; ++i) {
            af[i]  = *(const bf16x8*)(As + (mi_base + i * 16 + fr) * 32 + fq * 8);
            bfr[i] = *(const bf16x8*)(Bs + (ni_base + i * 16 + fr) * 32 + fq * 8);
        }
#pragma unroll
        for (int i = 0; i < 4; ++i)
#pragma unroll
            for (int j = 0; j < 4; ++j)
                acc[i][j] = __builtin_amdgcn_mfma_f32_16x16x32_bf16(
                    af[i], bfr[j], acc[i][j], 0, 0, 0);
    }

    if (VEC) {
        __syncthreads();
        bf16* tile = (bf16*)smem;
#pragma unroll
        for (int i = 0; i < 4; ++i)
#pragma unroll
            for (int j = 0; j < 4; ++j)
#pragma unroll
                for (int r = 0; r < 4; ++r) {
                    const int rl = mi_base + i * 16 + fq * 4 + r;
                    const int cl = ni_base + j * 16 + fr;
                    tile[rl * EPI_LD + cl] = (bf16)acc[i][j][r];
                }
        __syncthreads();
#pragma unroll
        for (int k = 0; k < 8; ++k) {
            const int rl = (tid >> 3) + 32 * (k >> 1);
            const int cl = (tid & 7) * 8 + 64 * (k & 1);
            const bf16x8 v = *(const bf16x8*)(tile + rl * EPI_LD + cl);
            *(bf16x8*)((bf16*)C + (long)(row0 + rl) * ldc + col0 + cl) = v;
        }
    } else {
#pragma unroll
        for (int i = 0; i < 4; ++i)
#pragma unroll
            for (int j = 0; j < 4; ++j)
#pragma unroll
                for (int r = 0; r < 4; ++r) {
                    const long row = row0 + mi_base + i * 16 + fq * 4 + r;
                    const long cg  = col0 + ni_base + j * 16 + fr;
                    C[row * ldc + cg] = (OUT)acc[i][j][r];
                }
    }
}

// ---------------------------------------------------------------------------
// 8) h = bf16(relu(ybase + ysp[slot0] + ysp[slot1])^2); one block per token
// ---------------------------------------------------------------------------
__global__ __launch_bounds__(256) void relu2_gather(
    const bf16* __restrict__ Yb,   // [N_TOK][O_DIM]
    const bf16* __restrict__ ysp,  // [2*N_TOK][O_DIM]
    const int* __restrict__ pos,   // [N_TOK][2]
    const int* __restrict__ off,   // [G_DIM]
    bf16* __restrict__ H)          // [N_TOK][O_DIM]
{
    const int t  = blockIdx.x;
    const int p0 = pos[t * 2];
    const int p1 = pos[t * 2 + 1];
    const long r0 = off[p0 >> 16] + (p0 & 0xffff);
    const long r1 = off[p1 >> 16] + (p1 & 0xffff);
    const int c = threadIdx.x * 16;

    const bf16* yb = Yb + (long)t * O_DIM + c;
    const bf16* s0 = ysp + r0 * O_DIM + c;
    const bf16* s1 = ysp + r1 * O_DIM + c;
    bf16* hp = H + (long)t * O_DIM + c;

#pragma unroll
    for (int h = 0; h < 2; ++h) {
        const bf16x8 a = *(const bf16x8*)(yb + h * 8);
        const bf16x8 b = *(const bf16x8*)(s0 + h * 8);
        const bf16x8 d = *(const bf16x8*)(s1 + h * 8);
        bf16x8 o;
#pragma unroll
        for (int k = 0; k < 8; ++k) {
            float v = (float)a[k] + (float)b[k] + (float)d[k];
            v = fmaxf(v, 0.f);
            o[k] = (bf16)(v * v);
        }
        *(bf16x8*)(hp + h * 8) = o;
    }
}

// ---------------------------------------------------------------------------
extern "C" void kernel_launch(void* const* d_in, const int* in_sizes, int n_in,
                              void* d_out, int out_size, void* d_ws, size_t ws_size,
                              hipStream_t stream)
{
    const float* X  = (const float*)d_in[0];  // [4,2048,1024]
    const float* WG = (const float*)d_in[1];  // [1024,8]
    const float* Wi = (const float*)d_in[2];  // [8,1024,4096] == [8192][4096]
    const float* dn = (const float*)d_in[3];  // [4096,1024]
    float* out = (float*)d_out;               // [8192][1024] fp32

    char* ws = (char*)d_ws;
    const long MB = 1l << 20;
    int*   cnt   = (int*)ws;                        // 32 B
    int*   off   = (int*)(ws + 1024);               // 32 B
    int*   offp  = (int*)(ws + 2048);               // 36 B
    int*   pos   = (int*)(ws + 4096);               // 64 KB
    int*   tok   = (int*)(ws + 128 * 1024);         // 256 KB
    float* scl   = (float*)(ws + 448 * 1024);       // 256 KB
    int*   sel   = (int*)(ws + 704 * 1024);         // 64 KB
    float* sval  = (float*)(ws + 768 * 1024);       // 64 KB
    bf16*  dnT   = (bf16*)(ws + 1 * MB);            // 8 MB
    bf16*  WiT   = (bf16*)(ws + 9 * MB);            // 64 MB
    bf16*  Hh    = (bf16*)(ws + 9 * MB);            // 64 MB (aliases WiT; dead by then)
    bf16*  Xs    = (bf16*)(ws + 73 * MB);           // 34 MB (17408 slots; 256-row
                                                    //  tile slack reads spill into Yb)
    bf16*  Yb    = (bf16*)(ws + 107 * MB);          // 64 MB
    bf16*  ysp   = (bf16*)(ws + 171 * MB);          // 128 MB -> 299 MB high water
    bf16*  Xb    = (bf16*)(ws + 171 * MB);          // 16 MB (overlaid by ysp AFTER gather)
    bf16*  WsumT = (bf16*)(ws + 187 * MB);          // 8 MB  (overlaid by ysp after base gemm)

    gate_compute<<<dim3(N_TOK / 4), dim3(256), 0, stream>>>(X, WG, sel, sval);
    route_kernel<<<dim3(1), dim3(1024), 0, stream>>>(sel, sval, cnt, off, offp,
                                                     tok, scl, pos);
    convert_x<<<dim3(N_TOK * E_DIM / 1024), dim3(256), 0, stream>>>(X, Xb);
    transpose_conv<<<dim3(8192 / 64, O_DIM / 64), dim3(256), 0, stream>>>(Wi, WiT, 8192, O_DIM);
    transpose_conv<<<dim3(O_DIM / 64, E_DIM / 64), dim3(256), 0, stream>>>(dn, dnT, O_DIM, E_DIM);
    wsum_kernel<<<dim3(O_DIM), dim3(256), 0, stream>>>(WiT, WsumT);
    // y_base = Xb @ WsumT^T  (bf16 out); 32 mtiles x 16 coltiles, 256^2 core
    gemm256_base<<<dim3(512), dim3(512), 0, stream>>>(Xb, WsumT, Yb);
    // expert-sorted padded copy of X (after base gemm: Xb/WsumT then dead)
    gather_rows<<<dim3(17408), dim3(128), 0, stream>>>(Xb, cnt, offp, tok, Xs);
    // slot partials: scale * sortedX @ Wi[g]  (ysp overlays Xb/WsumT)
    gemm256_sparse<<<dim3(8192), dim3(512), 0, stream>>>(
        Xs, WiT, cnt, off, offp, scl, ysp);
    relu2_gather<<<dim3(N_TOK), dim3(256), 0, stream>>>(Yb, ysp, pos, off, Hh);
    // out = Hh @ dnT^T  (fp32 out); 64 mtiles x 8 coltiles (legacy 128^2)
    gemm_mt<float, false><<<dim3(64 * 8), dim3(256), 0, stream>>>(
        Hh, O_DIM, dnT, O_DIM, out, E_DIM, O_DIM);
}

// Round 2
// 720.244 us; speedup vs baseline: 1.0308x; 1.0308x over previous
//
#include <hip/hip_runtime.h>
#include <hip/hip_bf16.h>
#include <math.h>

typedef __bf16 bf16;
typedef __bf16 bf16x4 __attribute__((ext_vector_type(4)));
typedef __bf16 bf16x8 __attribute__((ext_vector_type(8)));
typedef float  floatx4 __attribute__((ext_vector_type(4)));

#define N_TOK 8192   // B*S
#define E_DIM 1024
#define G_DIM 8
#define O_DIM 4096
#define EPI_LD 132   // padded leading dim of epilogue LDS tile (bf16) for old gemm

__device__ __forceinline__ void gload_lds16(const void* g, void* l) {
    __builtin_amdgcn_global_load_lds(
        (__attribute__((address_space(1))) void*)(g),
        (__attribute__((address_space(3))) void*)(l),
        16, 0, 0);
}

// ---------------------------------------------------------------------------
// 1) gate = X @ WG; top-2. NO atomics: writes per-entry expert id + scale.
// ---------------------------------------------------------------------------
__global__ __launch_bounds__(256) void gate_compute(
    const float* __restrict__ X,   // [N_TOK][E_DIM]
    const float* __restrict__ WG,  // [E_DIM][G_DIM]
    int* __restrict__ sel,         // [N_TOK*2] expert id
    float* __restrict__ sval)      // [N_TOK*2] sigmoid-0.5
{
    __shared__ float lwgT[G_DIM * E_DIM];   // [g][e], 32 KB
    const int tid  = threadIdx.x;
    const int wave = tid >> 6;
    const int lane = tid & 63;

#pragma unroll
    for (int k = 0; k < 8; ++k) {
        const int i = k * 256 + tid;
        const float4 v = *(const float4*)(WG + i * 4);
        const int e  = i >> 1;
        const int g0 = (i & 1) * 4;
        lwgT[(g0 + 0) * E_DIM + e] = v.x;
        lwgT[(g0 + 1) * E_DIM + e] = v.y;
        lwgT[(g0 + 2) * E_DIM + e] = v.z;
        lwgT[(g0 + 3) * E_DIM + e] = v.w;
    }
    __syncthreads();

    const int t = blockIdx.x * 4 + wave;
    float acc[G_DIM];
#pragma unroll
    for (int g = 0; g < G_DIM; ++g) acc[g] = 0.f;

#pragma unroll
    for (int it = 0; it < 4; ++it) {
        const int e0 = it * 256 + lane * 4;
        const float4 xv = *(const float4*)(X + (long)t * E_DIM + e0);
#pragma unroll
        for (int g = 0; g < G_DIM; ++g) {
            const float4 wv = *(const float4*)(lwgT + g * E_DIM + e0);
            acc[g] += xv.x * wv.x + xv.y * wv.y + xv.z * wv.z + xv.w * wv.w;
        }
    }
#pragma unroll
    for (int g = 0; g < G_DIM; ++g) {
        float v = acc[g];
#pragma unroll
        for (int off = 32; off > 0; off >>= 1) v += __shfl_down(v, off, 64);
        acc[g] = v;  // valid on lane 0
    }
    if (lane == 0) {
        int i1 = 0;
#pragma unroll
        for (int g = 1; g < G_DIM; ++g) if (acc[g] > acc[i1]) i1 = g;
        int i2 = (i1 == 0) ? 1 : 0;
#pragma unroll
        for (int g = 0; g < G_DIM; ++g)
            if (g != i1 && g != i2 && acc[g] > acc[i2]) i2 = g;
#pragma unroll
        for (int s = 0; s < 2; ++s) {
            const int g = s ? i2 : i1;
            sel[t * 2 + s]  = g;
            sval[t * 2 + s] = 1.f / (1.f + expf(-acc[g])) - 0.5f;
        }
    }
}

// ---------------------------------------------------------------------------
// 1b) routing: ballot histogram + prefix + stable scatter. 1 block x 1024.
// ---------------------------------------------------------------------------
__global__ __launch_bounds__(1024) void route_kernel(
    const int* __restrict__ sel, const float* __restrict__ sval,
    int* __restrict__ cnt, int* __restrict__ off, int* __restrict__ offp,
    int* __restrict__ tok, float* __restrict__ scl, int* __restrict__ pos)
{
    __shared__ int hcnt[16][G_DIM];
    __shared__ int wbase[16][G_DIM];
    const int tid  = threadIdx.x;
    const int w    = tid >> 6;
    const int lane = tid & 63;
    const unsigned long long below = ((unsigned long long)1 << lane) - 1;

    int c0[G_DIM];
#pragma unroll
    for (int g = 0; g < G_DIM; ++g) c0[g] = 0;
    for (int c = 0; c < 16; ++c) {
        const int g = sel[w * 1024 + c * 64 + lane];
#pragma unroll
        for (int gg = 0; gg < G_DIM; ++gg)
            c0[gg] += __popcll(__ballot(g == gg));
    }
    if (lane == 0)
#pragma unroll
        for (int g = 0; g < G_DIM; ++g) hcnt[w][g] = c0[g];
    __syncthreads();

    if (tid == 0) {
        int tot[G_DIM];
#pragma unroll
        for (int g = 0; g < G_DIM; ++g) {
            int a = 0;
            for (int ww = 0; ww < 16; ++ww) { wbase[ww][g] = a; a += hcnt[ww][g]; }
            tot[g] = a; cnt[g] = a;
        }
        int a = 0, b = 0;
#pragma unroll
        for (int g = 0; g < G_DIM; ++g) {
            off[g]  = a; a += tot[g];
            offp[g] = b; b += (tot[g] + 127) & ~127;
        }
        offp[G_DIM] = b;
    }
    __syncthreads();

    int run[G_DIM];
#pragma unroll
    for (int g = 0; g < G_DIM; ++g) run[g] = 0;
    for (int c = 0; c < 16; ++c) {
        const int idx = w * 1024 + c * 64 + lane;
        const int g   = sel[idx];
        const float sv = sval[idx];
        int myrank = 0;
#pragma unroll
        for (int gg = 0; gg < G_DIM; ++gg) {
            const unsigned long long m = __ballot(g == gg);
            const int r = run[gg] + __popcll(m & below);
            if (g == gg) myrank = r;
            run[gg] += __popcll(m);
        }
        const int p = wbase[w][g] + myrank;
        tok[g * N_TOK + p] = idx >> 1;
        scl[g * N_TOK + p] = sv;
        pos[idx] = (g << 16) | p;
    }
}

// ---------------------------------------------------------------------------
// 2) X fp32 -> bf16
// ---------------------------------------------------------------------------
__global__ __launch_bounds__(256) void convert_x(
    const float* __restrict__ X, bf16* __restrict__ Xb)
{
    const long i = ((long)blockIdx.x * 256 + threadIdx.x) * 4;
    const float4 v = *(const float4*)(X + i);
    bf16x4 o;
    o[0] = (bf16)v.x; o[1] = (bf16)v.y; o[2] = (bf16)v.z; o[3] = (bf16)v.w;
    *(bf16x4*)(Xb + i) = o;
}

// ---------------------------------------------------------------------------
// 3) transpose + fp32->bf16: S[R][C] -> D[C][R]
// ---------------------------------------------------------------------------
__global__ __launch_bounds__(256) void transpose_conv(
    const float* __restrict__ S, bf16* __restrict__ D, int R, int C)
{
    __shared__ float tile[64][65];
    const int r0  = blockIdx.x * 64;
    const int c0  = blockIdx.y * 64;
    const int tid = threadIdx.x;
    const int tr  = tid >> 4;          // 0..15
    const int tc4 = (tid & 15) * 4;    // 0..60

#pragma unroll
    for (int p = 0; p < 4; ++p) {
        const int r = p * 16 + tr;
        const float4 v = *(const float4*)(S + (long)(r0 + r) * C + c0 + tc4);
        tile[r][tc4 + 0] = v.x;
        tile[r][tc4 + 1] = v.y;
        tile[r][tc4 + 2] = v.z;
        tile[r][tc4 + 3] = v.w;
    }
    __syncthreads();
#pragma unroll
    for (int p = 0; p < 4; ++p) {
        const int c = p * 16 + tr;     // source col == dest row
        bf16x4 o;
        o[0] = (bf16)tile[tc4 + 0][c];
        o[1] = (bf16)tile[tc4 + 1][c];
        o[2] = (bf16)tile[tc4 + 2][c];
        o[3] = (bf16)tile[tc4 + 3][c];
        *(bf16x4*)(D + (long)(c0 + c) * R + r0 + tc4) = o;
    }
}

// ---------------------------------------------------------------------------
// 4) WsumT[o][e] = 0.5 * sum_g WiT[o][g*1024+e]   (bf16)
// ---------------------------------------------------------------------------
__global__ __launch_bounds__(256) void wsum_kernel(
    const bf16* __restrict__ WiT, bf16* __restrict__ WsumT)
{
    const int o  = blockIdx.x;
    const int e4 = threadIdx.x * 4;
    float a0 = 0.f, a1 = 0.f, a2 = 0.f, a3 = 0.f;
#pragma unroll
    for (int g = 0; g < G_DIM; ++g) {
        const bf16x4 v = *(const bf16x4*)(WiT + (long)o * 8192 + g * E_DIM + e4);
        a0 += (float)v[0]; a1 += (float)v[1]; a2 += (float)v[2]; a3 += (float)v[3];
    }
    bf16x4 w;
    w[0] = (bf16)(0.5f * a0); w[1] = (bf16)(0.5f * a1);
    w[2] = (bf16)(0.5f * a2); w[3] = (bf16)(0.5f * a3);
    *(bf16x4*)(WsumT + (long)o * E_DIM + e4) = w;
}

// ---------------------------------------------------------------------------
// 5) gather rows of Xb into expert-sorted, 128-padded Xs. One block per slot.
// ---------------------------------------------------------------------------
__global__ __launch_bounds__(128) void gather_rows(
    const bf16* __restrict__ Xb, const int* __restrict__ cnt,
    const int* __restrict__ offp, const int* __restrict__ tok,
    bf16* __restrict__ Xs)
{
    const int slot = blockIdx.x;
    if (slot >= offp[G_DIM]) return;
    int g = 0;
    while (slot >= offp[g + 1]) ++g;
    const int p = slot - offp[g];
    bf16* dst = Xs + (long)slot * E_DIM + threadIdx.x * 8;
    if (p < cnt[g]) {
        const bf16* src = Xb + (long)tok[g * N_TOK + p] * E_DIM + threadIdx.x * 8;
        *(bf16x8*)dst = *(const bf16x8*)src;
    } else {
        bf16x8 z = {};
        *(bf16x8*)dst = z;
    }
}

// ---------------------------------------------------------------------------
// 6) 256x256 / BK=64 / 8-wave GEMM core, m201-style per-phase schedule.
//    4 phases per K-tile: {ds_read subtile + stage 1 half-tile -> bar ->
//    lgkmcnt(0) -> setprio(1) -> 16 MFMA -> setprio(0) -> bar}, counted
//    vmcnt(8) only at phases 2 and 4.
//    LDS 8 x 16KB slots: slot(buf, A/B, kh) = buf*64K + AB*32K + kh*16K.
//    A slot holds [256 rows][32 k] bf16 (64B rows); k16-chunk s of row r holds
//    global k16 chunk s ^ ((r>>1)&3)  (involution; applied to the global
//    source at staging and to the ds_read address -> 2 lanes/bank-group).
//    Half-tile lifetime: kh0 slots die after phase 2, kh1 after phase 4, so
//    phases 3/4 stage tile t+2 kh0 into the CURRENT buffer and phases 1/2
//    stage tile t+1 kh1 into the other buffer: every stage has >=4 phases of
//    flight before its consumer, and vmcnt(8) (4 half-tiles) covers it.
//    Tail phases stage clamped (redundant) half-tiles to keep FIFO counting
//    uniform; core exits with vmcnt(0)+barrier so the epilogue may reuse LDS.
// ---------------------------------------------------------------------------
__device__ __forceinline__ void gemm_core256(
    const bf16* __restrict__ Ap, long lda,
    const bf16* __restrict__ Bp, long ldb,
    int K, char* smem, floatx4 (&acc)[8][4])
{
    const int tid  = threadIdx.x;
    const int wave = tid >> 6;
    const int lane = tid & 63;
    const int wm   = wave >> 2;     // 0..1  (wave row)
    const int wn   = wave & 3;      // 0..3  (wave col)
    const int fr   = lane & 15;
    const int fq   = lane >> 4;

#pragma unroll
    for (int i = 0; i < 8; ++i)
#pragma unroll
        for (int j = 0; j < 4; ++j)
            acc[i][j] = (floatx4){0.f, 0.f, 0.f, 0.f};

    // ---- staging geometry: thread covers rows (tid>>2) and (tid>>2)+128,
    //      16B chunk (tid&3) of the 64B kh-row; source chunk pre-swizzled ----
    const int  srow = tid >> 2;                               // 0..127
    const int  ksw  = (((tid & 3) ^ ((tid >> 3) & 3)) << 4);  // source byte in 64B row
    const char* sa  = (const char*)Ap + (long)srow * (lda * 2) + ksw;
    const char* sb  = (const char*)Bp + (long)srow * (ldb * 2) + ksw;
    const long aR   = lda * 256;    // +128 rows (bytes)
    const long bR   = ldb * 256;
    const int  ldsW = wave * 1024;  // wave-uniform LDS sub-base

#define STAGE_H(sbase, src, rstr, kb) do {                                   \
        gload_lds16((src) + (kb),          smem + (sbase) + ldsW);           \
        gload_lds16((src) + (kb) + (rstr), smem + (sbase) + 8192 + ldsW);    \
    } while (0)

    // ---- compute-side LDS offsets (swizzled reads) ----
    const int asw = ((fq ^ ((fr >> 1) & 3)) << 4);
    const int aro = (wm * 128 + fr) * 64 + asw;   // byte offset inside A slot
    const int bro = (wn * 64 + fr) * 64 + asw;    // byte offset inside B slot

    const int nt = K >> 6;

    // ---- prologue: tile0 all 4 half-tiles, then tile1 kh0 (B, A) ----
    {
        const long k1 = (nt > 1) ? 128 : 0;
        STAGE_H(0,             sa, aR, 0);      // t0 A kh0
        STAGE_H(32768,         sb, bR, 0);      // t0 B kh0
        STAGE_H(16384,         sa, aR, 64);     // t0 A kh1
        STAGE_H(49152,         sb, bR, 64);     // t0 B kh1
        STAGE_H(65536 + 32768, sb, bR, k1);     // t1 B kh0
        STAGE_H(65536 + 0,     sa, aR, k1);     // t1 A kh0
    }
    asm volatile("s_waitcnt vmcnt(4)" ::: "memory");   // tile0 fully landed
    __builtin_amdgcn_s_barrier();
    __builtin_amdgcn_sched_barrier(0);

#define LD8(v, off) (v) = *(const bf16x8*)(smem + (off))
#define PHASE_MID() do {                                                     \
        __builtin_amdgcn_sched_barrier(0);                                   \
        __builtin_amdgcn_s_barrier();                                        \
        asm volatile("s_waitcnt lgkmcnt(0)" ::: "memory");                   \
        __builtin_amdgcn_sched_barrier(0);                                   \
    } while (0)
#define PHASE_END() do {                                                     \
        __builtin_amdgcn_sched_barrier(0);                                   \
        __builtin_amdgcn_s_barrier();                                        \
        __builtin_amdgcn_sched_barrier(0);                                   \
    } while (0)
#define PHASE_END_V() do {                                                   \
        __builtin_amdgcn_sched_barrier(0);                                   \
        asm volatile("s_waitcnt vmcnt(8)" ::: "memory");                     \
        __builtin_amdgcn_s_barrier();                                        \
        __builtin_amdgcn_sched_barrier(0);                                   \
    } while (0)

    bf16x8 af[4], bq[4];

    for (int t = 0; t < nt; ++t) {
        const int  bo  = (t & 1) << 16;
        const int  nbo = bo ^ 65536;
        const long k1  = (long)((t + 1 < nt) ? t + 1 : nt - 1) * 128;
        const long k2  = (long)((t + 2 < nt) ? t + 2 : nt - 1) * 128;

        // ===== phase 1: kh0, wave-rows 0-63 =====
#pragma unroll
        for (int i = 0; i < 4; ++i) LD8(af[i], bo + aro + i * 1024);
#pragma unroll
        for (int j = 0; j < 4; ++j) LD8(bq[j], bo + 32768 + bro + j * 1024);
        STAGE_H(nbo + 49152, sb, bR, k1 + 64);          // (t+1) B kh1
        PHASE_MID();
        __builtin_amdgcn_s_setprio(1);
#pragma unroll
        for (int i = 0; i < 4; ++i)
#pragma unroll
            for (int j = 0; j < 4; ++j)
                acc[i][j] = __builtin_amdgcn_mfma_f32_16x16x32_bf16(
                    af[i], bq[j], acc[i][j], 0, 0, 0);
        __builtin_amdgcn_s_setprio(0);
        PHASE_END();

        // ===== phase 2: kh0, wave-rows 64-127 (reuse bq) =====
#pragma unroll
        for (int i = 0; i < 4; ++i) LD8(af[i], bo + aro + 4096 + i * 1024);
        STAGE_H(nbo + 16384, sa, aR, k1 + 64);          // (t+1) A kh1
        PHASE_MID();
        __builtin_amdgcn_s_setprio(1);
#pragma unroll
        for (int i = 0; i < 4; ++i)
#pragma unroll
            for (int j = 0; j < 4; ++j)
                acc[4 + i][j] = __builtin_amdgcn_mfma_f32_16x16x32_bf16(
                    af[i], bq[j], acc[4 + i][j], 0, 0, 0);
        __builtin_amdgcn_s_setprio(0);
        PHASE_END_V();                                   // covers (t) kh1

        // ===== phase 3: kh1, wave-rows 0-63 =====
#pragma unroll
        for (int i = 0; i < 4; ++i) LD8(af[i], bo + 16384 + aro + i * 1024);
#pragma unroll
        for (int j = 0; j < 4; ++j) LD8(bq[j], bo + 49152 + bro + j * 1024);
        STAGE_H(bo + 32768, sb, bR, k2);                 // (t+2) B kh0
        PHASE_MID();
        __builtin_amdgcn_s_setprio(1);
#pragma unroll
        for (int i = 0; i < 4; ++i)
#pragma unroll
            for (int j = 0; j < 4; ++j)
                acc[i][j] = __builtin_amdgcn_mfma_f32_16x16x32_bf16(
                    af[i], bq[j], acc[i][j], 0, 0, 0);
        __builtin_amdgcn_s_setprio(0);
        PHASE_END();

        // ===== phase 4: kh1, wave-rows 64-127 (reuse bq) =====
#pragma unroll
        for (int i = 0; i < 4; ++i) LD8(af[i], bo + 16384 + aro + 4096 + i * 1024);
        STAGE_H(bo + 0, sa, aR, k2);                     // (t+2) A kh0
        PHASE_MID();
        __builtin_amdgcn_s_setprio(1);
#pragma unroll
        for (int i = 0; i < 4; ++i)
#pragma unroll
            for (int j = 0; j < 4; ++j)
                acc[4 + i][j] = __builtin_amdgcn_mfma_f32_16x16x32_bf16(
                    af[i], bq[j], acc[4 + i][j], 0, 0, 0);
        __builtin_amdgcn_s_setprio(0);
        PHASE_END_V();                                   // covers (t+1) kh0
    }

    // drain stray (clamped) stages before the caller reuses LDS
    asm volatile("s_waitcnt vmcnt(0)" ::: "memory");
    __builtin_amdgcn_s_barrier();
#undef STAGE_H
#undef LD8
#undef PHASE_MID
#undef PHASE_END
#undef PHASE_END_V
}

// ---------------------------------------------------------------------------
// 6a) base GEMM: Yb = Xb @ WsumT^T  (bf16 out), M=8192 N=4096 K=1024.
//     grid 512 = 32 mtiles x 16 coltiles; same-B-panel blocks on one XCD.
// ---------------------------------------------------------------------------
__global__ __launch_bounds__(512, 2) void gemm256_base(
    const bf16* __restrict__ A, const bf16* __restrict__ BT,
    bf16* __restrict__ C)
{
    __shared__ __align__(16) char smem[131072];
    const int u   = blockIdx.x;
    const int xcd = u & 7;
    const int s   = u >> 3;
    const int mt  = s & 31;
    const int ct  = xcd + 8 * (s >> 5);
    const int row0 = mt * 256, col0 = ct * 256;

    floatx4 acc[8][4];
    gemm_core256(A + (long)row0 * E_DIM, E_DIM,
                 BT + (long)col0 * E_DIM, E_DIM,
                 E_DIM, smem, acc);

    const int tid = threadIdx.x, wave = tid >> 6, lane = tid & 63;
    const int wm = wave >> 2, wn = wave & 3, fr = lane & 15, fq = lane >> 4;
    bf16* tile = (bf16*)smem;
#pragma unroll
    for (int i = 0; i < 8; ++i)
#pragma unroll
        for (int j = 0; j < 4; ++j)
#pragma unroll
            for (int r = 0; r < 4; ++r)
                tile[(wm * 128 + i * 16 + fq * 4 + r) * 256 + wn * 64 + j * 16 + fr] =
                    (bf16)(acc[i][j][r]);
    __syncthreads();
#pragma unroll
    for (int k = 0; k < 16; ++k) {
        const int rl = (tid >> 5) + k * 16;
        const int cc = (tid & 31) * 8;
        *(bf16x8*)(C + (long)(row0 + rl) * O_DIM + col0 + cc) =
            *(const bf16x8*)(tile + rl * 256 + cc);
    }
}

// ---------------------------------------------------------------------------
// 6b) sparse grouped GEMM on sorted A (256x256 tiles). Tiles may straddle an
//     expert's 128-padded boundary: straddling rows compute garbage that the
//     store mask drops. End-of-Xs slack reads land in the allocated Yb region.
//     grid 8192 = 8 experts x 64 mtiles x 16 coltiles, expert g pinned to XCD g.
// ---------------------------------------------------------------------------
__global__ __launch_bounds__(512, 2) void gemm256_sparse(
    const bf16* __restrict__ Xs,   // [padded slots][E_DIM]
    const bf16* __restrict__ WiT,  // [O_DIM][8192]
    const int* __restrict__ cnt,
    const int* __restrict__ off,
    const int* __restrict__ offp,
    const float* __restrict__ scl,
    bf16* __restrict__ ysp)        // [2*N_TOK][O_DIM] compact
{
    const int u   = blockIdx.x;
    const int xcd = u & 7;
    const int s   = u >> 3;
    const int mt  = s & 63;
    const int pc  = xcd + 8 * (s >> 6);   // [0,128)
    const int g   = pc & 7;
    const int ct  = pc >> 3;              // [0,16)

    const int cg     = cnt[g];
    const int base_p = offp[g];
    const int cgp    = offp[g + 1] - base_p;
    const int m0     = mt * 256;
    if (m0 >= cgp) return;

    __shared__ __align__(16) char smem[131072];
    const int col0 = ct * 256;

    floatx4 acc[8][4];
    gemm_core256(Xs + (long)(base_p + m0) * E_DIM, E_DIM,
                 WiT + (long)col0 * 8192 + g * E_DIM, 8192,
                 E_DIM, smem, acc);

    const int tid = threadIdx.x, wave = tid >> 6, lane = tid & 63;
    const int wm = wave >> 2, wn = wave & 3, fr = lane & 15, fq = lane >> 4;
    const float* sclg = scl + g * N_TOK;
    const int clmax = cg - 1;
    bf16* tile = (bf16*)smem;
#pragma unroll
    for (int i = 0; i < 8; ++i)
#pragma unroll
        for (int r = 0; r < 4; ++r) {
            const int rl = wm * 128 + i * 16 + fq * 4 + r;
            const int gm = m0 + rl;
            const float sv = sclg[gm > clmax ? clmax : gm];
#pragma unroll
            for (int j = 0; j < 4; ++j)
                tile[rl * 256 + wn * 64 + j * 16 + fr] = (bf16)(sv * acc[i][j][r]);
        }
    __syncthreads();
    const long ob = off[g] + m0;
#pragma unroll
    for (int k = 0; k < 16; ++k) {
        const int rl = (tid >> 5) + k * 16;
        if (m0 + rl < cg) {
            const int cc = (tid & 31) * 8;
            *(bf16x8*)(ysp + (ob + rl) * O_DIM + col0 + cc) =
                *(const bf16x8*)(tile + rl * 256 + cc);
        }
    }
}

// ---------------------------------------------------------------------------
// 6c) legacy 128x128 dense GEMM (kept for the down projection: N=1024 would
//     give only 128 blocks at 256x256).
// ---------------------------------------------------------------------------
template <typename OUT, bool VEC>
__global__ __launch_bounds__(256, 4) void gemm_mt(
    const bf16* __restrict__ A, int lda,
    const bf16* __restrict__ BT, int ldb,
    OUT* __restrict__ C, int ldc, int K)
{
    __shared__ char smem[VEC ? (128 * EPI_LD * 2) : 16384];
    bf16* As = (bf16*)smem;
    bf16* Bs = (bf16*)(smem + 8192);

    const int u   = blockIdx.x;
    const int xcd = u & 7;
    const int s   = u >> 3;
    const int mt  = s & 63;
    const int col = xcd + 8 * (s >> 6);

    const int tid  = threadIdx.x;
    const int wave = tid >> 6;
    const int lane = tid & 63;
    const int row0 = mt * 128;
    const int col0 = col * 128;

    const int sr = lane >> 2;
    const int sc = (lane & 3) * 8;
    const bf16* agp0 = A  + (long)(row0 + 16 * wave       + sr) * lda + sc;
    const bf16* agp1 = A  + (long)(row0 + 16 * (wave + 4) + sr) * lda + sc;
    const bf16* bgp0 = BT + (long)(col0 + 16 * wave       + sr) * ldb + sc;
    const bf16* bgp1 = BT + (long)(col0 + 16 * (wave + 4) + sr) * ldb + sc;
    bf16* asl0 = As + (long)wave * 512;
    bf16* asl1 = As + (long)(wave + 4) * 512;
    bf16* bsl0 = Bs + (long)wave * 512;
    bf16* bsl1 = Bs + (long)(wave + 4) * 512;

    const int mi_base = (wave >> 1) * 64;
    const int ni_base = (wave & 1) * 64;
    const int fr = lane & 15;
    const int fq = lane >> 4;

    floatx4 acc[4][4] = {};

    for (int k0 = 0; k0 < K; k0 += 32) {
        __syncthreads();
        gload_lds16(agp0 + k0, (void*)asl0);
        gload_lds16(agp1 + k0, (void*)asl1);
        gload_lds16(bgp0 + k0, (void*)bsl0);
        gload_lds16(bgp1 + k0, (void*)bsl1);
        __syncthreads();

        bf16x8 af[4], bfr[4];
#pragma unroll
        for (int i = 0; i < 4; ++i) {
            af[i]  = *(const bf16x8*)(As + (mi_base + i * 16 + fr) * 32 + fq * 8);
            bfr[i] = *(const bf16x8*)(Bs + (ni_base + i * 16 + fr) * 32 + fq * 8);
        }
#pragma unroll
        for (int i = 0; i < 4; ++i)
#pragma unroll
            for (int j = 0; j < 4; ++j)
                acc[i][j] = __builtin_amdgcn_mfma_f32_16x16x32_bf16(
                    af[i], bfr[j], acc[i][j], 0, 0, 0);
    }

    if (VEC) {
        __syncthreads();
        bf16* tile = (bf16*)smem;
#pragma unroll
        for (int i = 0; i < 4; ++i)
#pragma unroll
            for (int j = 0; j < 4; ++j)
#pragma unroll
                for (int r = 0; r < 4; ++r) {
                    const int rl = mi_base + i * 16 + fq * 4 + r;
                    const int cl = ni_base + j * 16 + fr;
                    tile[rl * EPI_LD + cl] = (bf16)acc[i][j][r];
                }
        __syncthreads();
#pragma unroll
        for (int k = 0; k < 8; ++k) {
            const int rl = (tid >> 3) + 32 * (k >> 1);
            const int cl = (tid & 7) * 8 + 64 * (k & 1);
            const bf16x8 v = *(const bf16x8*)(tile + rl * EPI_LD + cl);
            *(bf16x8*)((bf16*)C + (long)(row0 + rl) * ldc + col0 + cl) = v;
        }
    } else {
#pragma unroll
        for (int i = 0; i < 4; ++i)
#pragma unroll
            for (int j = 0; j < 4; ++j)
#pragma unroll
                for (int r = 0; r < 4; ++r) {
                    const long row = row0 + mi_base + i * 16 + fq * 4 + r;
                    const long cg  = col0 + ni_base + j * 16 + fr;
                    C[row * ldc + cg] = (OUT)acc[i][j][r];
                }
    }
}

// ---------------------------------------------------------------------------
// 8) h = bf16(relu(ybase + ysp[slot0] + ysp[slot1])^2); one block per token
// ---------------------------------------------------------------------------
__global__ __launch_bounds__(256) void relu2_gather(
    const bf16* __restrict__ Yb,   // [N_TOK][O_DIM]
    const bf16* __restrict__ ysp,  // [2*N_TOK][O_DIM]
    const int* __restrict__ pos,   // [N_TOK][2]
    const int* __restrict__ off,   // [G_DIM]
    bf16* __restrict__ H)          // [N_TOK][O_DIM]
{
    const int t  = blockIdx.x;
    const int p0 = pos[t * 2];
    const int p1 = pos[t * 2 + 1];
    const long r0 = off[p0 >> 16] + (p0 & 0xffff);
    const long r1 = off[p1 >> 16] + (p1 & 0xffff);
    const int c = threadIdx.x * 16;

    const bf16* yb = Yb + (long)t * O_DIM + c;
    const bf16* s0 = ysp + r0 * O_DIM + c;
    const bf16* s1 = ysp + r1 * O_DIM + c;
    bf16* hp = H + (long)t * O_DIM + c;

#pragma unroll
    for (int h = 0; h < 2; ++h) {
        const bf16x8 a = *(const bf16x8*)(yb + h * 8);
        const bf16x8 b = *(const bf16x8*)(s0 + h * 8);
        const bf16x8 d = *(const bf16x8*)(s1 + h * 8);
        bf16x8 o;
#pragma unroll
        for (int k = 0; k < 8; ++k) {
            float v = (float)a[k] + (float)b[k] + (float)d[k];
            v = fmaxf(v, 0.f);
            o[k] = (bf16)(v * v);
        }
        *(bf16x8*)(hp + h * 8) = o;
    }
}

// ---------------------------------------------------------------------------
extern "C" void kernel_launch(void* const* d_in, const int* in_sizes, int n_in,
                              void* d_out, int out_size, void* d_ws, size_t ws_size,
                              hipStream_t stream)
{
    const float* X  = (const float*)d_in[0];  // [4,2048,1024]
    const float* WG = (const float*)d_in[1];  // [1024,8]
    const float* Wi = (const float*)d_in[2];  // [8,1024,4096] == [8192][4096]
    const float* dn = (const float*)d_in[3];  // [4096,1024]
    float* out = (float*)d_out;               // [8192][1024] fp32

    char* ws = (char*)d_ws;
    const long MB = 1l << 20;
    int*   cnt   = (int*)ws;                        // 32 B
    int*   off   = (int*)(ws + 1024);               // 32 B
    int*   offp  = (int*)(ws + 2048);               // 36 B
    int*   pos   = (int*)(ws + 4096);               // 64 KB
    int*   tok   = (int*)(ws + 128 * 1024);         // 256 KB
    float* scl   = (float*)(ws + 448 * 1024);       // 256 KB
    int*   sel   = (int*)(ws + 704 * 1024);         // 64 KB
    float* sval  = (float*)(ws + 768 * 1024);       // 64 KB
    bf16*  dnT   = (bf16*)(ws + 1 * MB);            // 8 MB
    bf16*  WiT   = (bf16*)(ws + 9 * MB);            // 64 MB
    bf16*  Hh    = (bf16*)(ws + 9 * MB);            // 64 MB (aliases WiT; dead by then)
    bf16*  Xs    = (bf16*)(ws + 73 * MB);           // 34 MB (17408 slots; 256-row
                                                    //  tile slack reads spill into Yb)
    bf16*  Yb    = (bf16*)(ws + 107 * MB);          // 64 MB
    bf16*  ysp   = (bf16*)(ws + 171 * MB);          // 128 MB -> 299 MB high water
    bf16*  Xb    = (bf16*)(ws + 171 * MB);          // 16 MB (overlaid by ysp AFTER gather)
    bf16*  WsumT = (bf16*)(ws + 187 * MB);          // 8 MB  (overlaid by ysp after base gemm)

    gate_compute<<<dim3(N_TOK / 4), dim3(256), 0, stream>>>(X, WG, sel, sval);
    route_kernel<<<dim3(1), dim3(1024), 0, stream>>>(sel, sval, cnt, off, offp,
                                                     tok, scl, pos);
    convert_x<<<dim3(N_TOK * E_DIM / 1024), dim3(256), 0, stream>>>(X, Xb);
    transpose_conv<<<dim3(8192 / 64, O_DIM / 64), dim3(256), 0, stream>>>(Wi, WiT, 8192, O_DIM);
    transpose_conv<<<dim3(O_DIM / 64, E_DIM / 64), dim3(256), 0, stream>>>(dn, dnT, O_DIM, E_DIM);
    wsum_kernel<<<dim3(O_DIM), dim3(256), 0, stream>>>(WiT, WsumT);
    // y_base = Xb @ WsumT^T  (bf16 out); 32 mtiles x 16 coltiles, 256^2 core
    gemm256_base<<<dim3(512), dim3(512), 0, stream>>>(Xb, WsumT, Yb);
    // expert-sorted padded copy of X (after base gemm: Xb/WsumT then dead)
    gather_rows<<<dim3(17408), dim3(128), 0, stream>>>(Xb, cnt, offp, tok, Xs);
    // slot partials: scale * sortedX @ Wi[g]  (ysp overlays Xb/WsumT)
    gemm256_sparse<<<dim3(8192), dim3(512), 0, stream>>>(
        Xs, WiT, cnt, off, offp, scl, ysp);
    relu2_gather<<<dim3(N_TOK), dim3(256), 0, stream>>>(Yb, ysp, pos, off, Hh);
    // out = Hh @ dnT^T  (fp32 out); 64 mtiles x 8 coltiles (legacy 128^2)
    gemm_mt<float, false><<<dim3(64 * 8), dim3(256), 0, stream>>>(
        Hh, O_DIM, dnT, O_DIM, out, E_DIM, O_DIM);
}

// Round 3
// 718.048 us; speedup vs baseline: 1.0339x; 1.0031x over previous
//
#include <hip/hip_runtime.h>
#include <hip/hip_bf16.h>
#include <math.h>

typedef __bf16 bf16;
typedef __bf16 bf16x4 __attribute__((ext_vector_type(4)));
typedef __bf16 bf16x8 __attribute__((ext_vector_type(8)));
typedef float  floatx4 __attribute__((ext_vector_type(4)));

#define N_TOK 8192   // B*S
#define E_DIM 1024
#define G_DIM 8
#define O_DIM 4096
#define EPI_LD 132   // padded leading dim of epilogue LDS tile (bf16) for old gemm

__device__ __forceinline__ void gload_lds16(const void* g, void* l) {
    __builtin_amdgcn_global_load_lds(
        (__attribute__((address_space(1))) void*)(g),
        (__attribute__((address_space(3))) void*)(l),
        16, 0, 0);
}

// ---------------------------------------------------------------------------
// 1) gate = X @ WG; top-2. NO atomics: writes per-entry expert id + scale.
// ---------------------------------------------------------------------------
__global__ __launch_bounds__(256) void gate_compute(
    const float* __restrict__ X,   // [N_TOK][E_DIM]
    const float* __restrict__ WG,  // [E_DIM][G_DIM]
    int* __restrict__ sel,         // [N_TOK*2] expert id
    float* __restrict__ sval)      // [N_TOK*2] sigmoid-0.5
{
    __shared__ float lwgT[G_DIM * E_DIM];   // [g][e], 32 KB
    const int tid  = threadIdx.x;
    const int wave = tid >> 6;
    const int lane = tid & 63;

#pragma unroll
    for (int k = 0; k < 8; ++k) {
        const int i = k * 256 + tid;
        const float4 v = *(const float4*)(WG + i * 4);
        const int e  = i >> 1;
        const int g0 = (i & 1) * 4;
        lwgT[(g0 + 0) * E_DIM + e] = v.x;
        lwgT[(g0 + 1) * E_DIM + e] = v.y;
        lwgT[(g0 + 2) * E_DIM + e] = v.z;
        lwgT[(g0 + 3) * E_DIM + e] = v.w;
    }
    __syncthreads();

    const int t = blockIdx.x * 4 + wave;
    float acc[G_DIM];
#pragma unroll
    for (int g = 0; g < G_DIM; ++g) acc[g] = 0.f;

#pragma unroll
    for (int it = 0; it < 4; ++it) {
        const int e0 = it * 256 + lane * 4;
        const float4 xv = *(const float4*)(X + (long)t * E_DIM + e0);
#pragma unroll
        for (int g = 0; g < G_DIM; ++g) {
            const float4 wv = *(const float4*)(lwgT + g * E_DIM + e0);
            acc[g] += xv.x * wv.x + xv.y * wv.y + xv.z * wv.z + xv.w * wv.w;
        }
    }
#pragma unroll
    for (int g = 0; g < G_DIM; ++g) {
        float v = acc[g];
#pragma unroll
        for (int off = 32; off > 0; off >>= 1) v += __shfl_down(v, off, 64);
        acc[g] = v;  // valid on lane 0
    }
    if (lane == 0) {
        int i1 = 0;
#pragma unroll
        for (int g = 1; g < G_DIM; ++g) if (acc[g] > acc[i1]) i1 = g;
        int i2 = (i1 == 0) ? 1 : 0;
#pragma unroll
        for (int g = 0; g < G_DIM; ++g)
            if (g != i1 && g != i2 && acc[g] > acc[i2]) i2 = g;
#pragma unroll
        for (int s = 0; s < 2; ++s) {
            const int g = s ? i2 : i1;
            sel[t * 2 + s]  = g;
            sval[t * 2 + s] = 1.f / (1.f + expf(-acc[g])) - 0.5f;
        }
    }
}

// ---------------------------------------------------------------------------
// 1b) routing: ballot histogram + prefix + stable scatter. 1 block x 1024.
// ---------------------------------------------------------------------------
__global__ __launch_bounds__(1024) void route_kernel(
    const int* __restrict__ sel, const float* __restrict__ sval,
    int* __restrict__ cnt, int* __restrict__ off, int* __restrict__ offp,
    int* __restrict__ tok, float* __restrict__ scl, int* __restrict__ pos)
{
    __shared__ int hcnt[16][G_DIM];
    __shared__ int wbase[16][G_DIM];
    const int tid  = threadIdx.x;
    const int w    = tid >> 6;
    const int lane = tid & 63;
    const unsigned long long below = ((unsigned long long)1 << lane) - 1;

    int c0[G_DIM];
#pragma unroll
    for (int g = 0; g < G_DIM; ++g) c0[g] = 0;
    for (int c = 0; c < 16; ++c) {
        const int g = sel[w * 1024 + c * 64 + lane];
#pragma unroll
        for (int gg = 0; gg < G_DIM; ++gg)
            c0[gg] += __popcll(__ballot(g == gg));
    }
    if (lane == 0)
#pragma unroll
        for (int g = 0; g < G_DIM; ++g) hcnt[w][g] = c0[g];
    __syncthreads();

    if (tid == 0) {
        int tot[G_DIM];
#pragma unroll
        for (int g = 0; g < G_DIM; ++g) {
            int a = 0;
            for (int ww = 0; ww < 16; ++ww) { wbase[ww][g] = a; a += hcnt[ww][g]; }
            tot[g] = a; cnt[g] = a;
        }
        int a = 0, b = 0;
#pragma unroll
        for (int g = 0; g < G_DIM; ++g) {
            off[g]  = a; a += tot[g];
            offp[g] = b; b += (tot[g] + 127) & ~127;
        }
        offp[G_DIM] = b;
    }
    __syncthreads();

    int run[G_DIM];
#pragma unroll
    for (int g = 0; g < G_DIM; ++g) run[g] = 0;
    for (int c = 0; c < 16; ++c) {
        const int idx = w * 1024 + c * 64 + lane;
        const int g   = sel[idx];
        const float sv = sval[idx];
        int myrank = 0;
#pragma unroll
        for (int gg = 0; gg < G_DIM; ++gg) {
            const unsigned long long m = __ballot(g == gg);
            const int r = run[gg] + __popcll(m & below);
            if (g == gg) myrank = r;
            run[gg] += __popcll(m);
        }
        const int p = wbase[w][g] + myrank;
        tok[g * N_TOK + p] = idx >> 1;
        scl[g * N_TOK + p] = sv;
        pos[idx] = (g << 16) | p;
    }
}

// ---------------------------------------------------------------------------
// 2) X fp32 -> bf16
// ---------------------------------------------------------------------------
__global__ __launch_bounds__(256) void convert_x(
    const float* __restrict__ X, bf16* __restrict__ Xb)
{
    const long i = ((long)blockIdx.x * 256 + threadIdx.x) * 4;
    const float4 v = *(const float4*)(X + i);
    bf16x4 o;
    o[0] = (bf16)v.x; o[1] = (bf16)v.y; o[2] = (bf16)v.z; o[3] = (bf16)v.w;
    *(bf16x4*)(Xb + i) = o;
}

// ---------------------------------------------------------------------------
// 3) transpose + fp32->bf16: S[R][C] -> D[C][R]
// ---------------------------------------------------------------------------
__global__ __launch_bounds__(256) void transpose_conv(
    const float* __restrict__ S, bf16* __restrict__ D, int R, int C)
{
    __shared__ float tile[64][65];
    const int r0  = blockIdx.x * 64;
    const int c0  = blockIdx.y * 64;
    const int tid = threadIdx.x;
    const int tr  = tid >> 4;          // 0..15
    const int tc4 = (tid & 15) * 4;    // 0..60

#pragma unroll
    for (int p = 0; p < 4; ++p) {
        const int r = p * 16 + tr;
        const float4 v = *(const float4*)(S + (long)(r0 + r) * C + c0 + tc4);
        tile[r][tc4 + 0] = v.x;
        tile[r][tc4 + 1] = v.y;
        tile[r][tc4 + 2] = v.z;
        tile[r][tc4 + 3] = v.w;
    }
    __syncthreads();
#pragma unroll
    for (int p = 0; p < 4; ++p) {
        const int c = p * 16 + tr;     // source col == dest row
        bf16x4 o;
        o[0] = (bf16)tile[tc4 + 0][c];
        o[1] = (bf16)tile[tc4 + 1][c];
        o[2] = (bf16)tile[tc4 + 2][c];
        o[3] = (bf16)tile[tc4 + 3][c];
        *(bf16x4*)(D + (long)(c0 + c) * R + r0 + tc4) = o;
    }
}

// ---------------------------------------------------------------------------
// 4) WsumT[o][e] = 0.5 * sum_g WiT[o][g*1024+e]   (bf16)
// ---------------------------------------------------------------------------
__global__ __launch_bounds__(256) void wsum_kernel(
    const bf16* __restrict__ WiT, bf16* __restrict__ WsumT)
{
    const int o  = blockIdx.x;
    const int e4 = threadIdx.x * 4;
    float a0 = 0.f, a1 = 0.f, a2 = 0.f, a3 = 0.f;
#pragma unroll
    for (int g = 0; g < G_DIM; ++g) {
        const bf16x4 v = *(const bf16x4*)(WiT + (long)o * 8192 + g * E_DIM + e4);
        a0 += (float)v[0]; a1 += (float)v[1]; a2 += (float)v[2]; a3 += (float)v[3];
    }
    bf16x4 w;
    w[0] = (bf16)(0.5f * a0); w[1] = (bf16)(0.5f * a1);
    w[2] = (bf16)(0.5f * a2); w[3] = (bf16)(0.5f * a3);
    *(bf16x4*)(WsumT + (long)o * E_DIM + e4) = w;
}

// ---------------------------------------------------------------------------
// 5) gather rows of Xb into expert-sorted, 128-padded Xs. One block per slot.
// ---------------------------------------------------------------------------
__global__ __launch_bounds__(128) void gather_rows(
    const bf16* __restrict__ Xb, const int* __restrict__ cnt,
    const int* __restrict__ offp, const int* __restrict__ tok,
    bf16* __restrict__ Xs)
{
    const int slot = blockIdx.x;
    if (slot >= offp[G_DIM]) return;
    int g = 0;
    while (slot >= offp[g + 1]) ++g;
    const int p = slot - offp[g];
    bf16* dst = Xs + (long)slot * E_DIM + threadIdx.x * 8;
    if (p < cnt[g]) {
        const bf16* src = Xb + (long)tok[g * N_TOK + p] * E_DIM + threadIdx.x * 8;
        *(bf16x8*)dst = *(const bf16x8*)src;
    } else {
        bf16x8 z = {};
        *(bf16x8*)dst = z;
    }
}

// ---------------------------------------------------------------------------
// 6) 256x256 / BK=64 / 8-wave GEMM core, per-phase ring schedule.
//    4 phases per K-tile: {ds_read subtile + stage 1 half-tile -> barrier ->
//    (compiler fine-grained lgkm waits) -> setprio(1) -> 16 MFMA ->
//    setprio(0) -> barrier}; counted vmcnt(8) only at phases 2 and 4.
//    NO sched_barrier / NO pinned lgkmcnt(0) in the loop (m141 lesson):
//    correctness against staging-overwrite is guaranteed by the >=4-phase
//    write->read distance in the slot ring plus the "memory"-clobbered vmcnt
//    asm fences at phases 2/4, which bound any compiler hoist/sink.
//    LDS 8 x 16KB slots: slot(buf, A/B, kh) = buf*64K + AB*32K + kh*16K.
//    A slot holds [256 rows][32 k] bf16 (64B rows); k16-chunk s of row r holds
//    global k16 chunk s ^ ((r>>1)&3)  (involution; applied to the global
//    source at staging and to the ds_read address).
// ---------------------------------------------------------------------------
__device__ __forceinline__ void gemm_core256(
    const bf16* __restrict__ Ap, long lda,
    const bf16* __restrict__ Bp, long ldb,
    int K, char* smem, floatx4 (&acc)[8][4])
{
    const int tid  = threadIdx.x;
    const int wave = tid >> 6;
    const int lane = tid & 63;
    const int wm   = wave >> 2;     // 0..1  (wave row)
    const int wn   = wave & 3;      // 0..3  (wave col)
    const int fr   = lane & 15;
    const int fq   = lane >> 4;

#pragma unroll
    for (int i = 0; i < 8; ++i)
#pragma unroll
        for (int j = 0; j < 4; ++j)
            acc[i][j] = (floatx4){0.f, 0.f, 0.f, 0.f};

    // ---- staging geometry: thread covers rows (tid>>2) and (tid>>2)+128,
    //      16B chunk (tid&3) of the 64B kh-row; source chunk pre-swizzled ----
    const int  srow = tid >> 2;                               // 0..127
    const int  ksw  = (((tid & 3) ^ ((tid >> 3) & 3)) << 4);  // source byte in 64B row
    const char* sa  = (const char*)Ap + (long)srow * (lda * 2) + ksw;
    const char* sb  = (const char*)Bp + (long)srow * (ldb * 2) + ksw;
    const long aR   = lda * 256;    // +128 rows (bytes)
    const long bR   = ldb * 256;
    const int  ldsW = wave * 1024;  // wave-uniform LDS sub-base

#define STAGE_H(sbase, src, rstr, kb) do {                                   \
        gload_lds16((src) + (kb),          smem + (sbase) + ldsW);           \
        gload_lds16((src) + (kb) + (rstr), smem + (sbase) + 8192 + ldsW);    \
    } while (0)

    // ---- compute-side LDS offsets (swizzled reads) ----
    const int asw = ((fq ^ ((fr >> 1) & 3)) << 4);
    const int aro = (wm * 128 + fr) * 64 + asw;   // byte offset inside A slot
    const int bro = (wn * 64 + fr) * 64 + asw;    // byte offset inside B slot

    const int nt = K >> 6;

    // ---- prologue: tile0 all 4 half-tiles, then tile1 kh0 (B, A) ----
    {
        const long k1 = (nt > 1) ? 128 : 0;
        STAGE_H(0,             sa, aR, 0);      // t0 A kh0
        STAGE_H(32768,         sb, bR, 0);      // t0 B kh0
        STAGE_H(16384,         sa, aR, 64);     // t0 A kh1
        STAGE_H(49152,         sb, bR, 64);     // t0 B kh1
        STAGE_H(65536 + 32768, sb, bR, k1);     // t1 B kh0
        STAGE_H(65536 + 0,     sa, aR, k1);     // t1 A kh0
    }
    asm volatile("s_waitcnt vmcnt(4)" ::: "memory");   // tile0 fully landed
    __builtin_amdgcn_s_barrier();

#define LD8(v, off) (v) = *(const bf16x8*)(smem + (off))
#define PHASE_MID()   __builtin_amdgcn_s_barrier()
#define PHASE_END()   __builtin_amdgcn_s_barrier()
#define PHASE_END_V() do {                                                   \
        asm volatile("s_waitcnt vmcnt(8)" ::: "memory");                     \
        __builtin_amdgcn_s_barrier();                                        \
    } while (0)

    bf16x8 af[4], bq[4];

    for (int t = 0; t < nt; ++t) {
        const int  bo  = (t & 1) << 16;
        const int  nbo = bo ^ 65536;
        const long k1  = (long)((t + 1 < nt) ? t + 1 : nt - 1) * 128;
        const long k2  = (long)((t + 2 < nt) ? t + 2 : nt - 1) * 128;

        // ===== phase 1: kh0, wave-rows 0-63 =====
#pragma unroll
        for (int i = 0; i < 4; ++i) LD8(af[i], bo + aro + i * 1024);
#pragma unroll
        for (int j = 0; j < 4; ++j) LD8(bq[j], bo + 32768 + bro + j * 1024);
        STAGE_H(nbo + 49152, sb, bR, k1 + 64);          // (t+1) B kh1
        PHASE_MID();
        __builtin_amdgcn_s_setprio(1);
#pragma unroll
        for (int i = 0; i < 4; ++i)
#pragma unroll
            for (int j = 0; j < 4; ++j)
                acc[i][j] = __builtin_amdgcn_mfma_f32_16x16x32_bf16(
                    af[i], bq[j], acc[i][j], 0, 0, 0);
        __builtin_amdgcn_s_setprio(0);
        PHASE_END();

        // ===== phase 2: kh0, wave-rows 64-127 (reuse bq) =====
#pragma unroll
        for (int i = 0; i < 4; ++i) LD8(af[i], bo + aro + 4096 + i * 1024);
        STAGE_H(nbo + 16384, sa, aR, k1 + 64);          // (t+1) A kh1
        PHASE_MID();
        __builtin_amdgcn_s_setprio(1);
#pragma unroll
        for (int i = 0; i < 4; ++i)
#pragma unroll
            for (int j = 0; j < 4; ++j)
                acc[4 + i][j] = __builtin_amdgcn_mfma_f32_16x16x32_bf16(
                    af[i], bq[j], acc[4 + i][j], 0, 0, 0);
        __builtin_amdgcn_s_setprio(0);
        PHASE_END_V();                                   // covers (t) kh1

        // ===== phase 3: kh1, wave-rows 0-63 =====
#pragma unroll
        for (int i = 0; i < 4; ++i) LD8(af[i], bo + 16384 + aro + i * 1024);
#pragma unroll
        for (int j = 0; j < 4; ++j) LD8(bq[j], bo + 49152 + bro + j * 1024);
        STAGE_H(bo + 32768, sb, bR, k2);                 // (t+2) B kh0
        PHASE_MID();
        __builtin_amdgcn_s_setprio(1);
#pragma unroll
        for (int i = 0; i < 4; ++i)
#pragma unroll
            for (int j = 0; j < 4; ++j)
                acc[i][j] = __builtin_amdgcn_mfma_f32_16x16x32_bf16(
                    af[i], bq[j], acc[i][j], 0, 0, 0);
        __builtin_amdgcn_s_setprio(0);
        PHASE_END();

        // ===== phase 4: kh1, wave-rows 64-127 (reuse bq) =====
#pragma unroll
        for (int i = 0; i < 4; ++i) LD8(af[i], bo + 16384 + aro + 4096 + i * 1024);
        STAGE_H(bo + 0, sa, aR, k2);                     // (t+2) A kh0
        PHASE_MID();
        __builtin_amdgcn_s_setprio(1);
#pragma unroll
        for (int i = 0; i < 4; ++i)
#pragma unroll
            for (int j = 0; j < 4; ++j)
                acc[4 + i][j] = __builtin_amdgcn_mfma_f32_16x16x32_bf16(
                    af[i], bq[j], acc[4 + i][j], 0, 0, 0);
        __builtin_amdgcn_s_setprio(0);
        PHASE_END_V();                                   // covers (t+1) kh0
    }

    // drain stray (clamped) stages before the caller reuses LDS
    asm volatile("s_waitcnt vmcnt(0)" ::: "memory");
    __builtin_amdgcn_s_barrier();
#undef STAGE_H
#undef LD8
#undef PHASE_MID
#undef PHASE_END
#undef PHASE_END_V
}

// ---------------------------------------------------------------------------
// 6a) base GEMM: Yb = Xb @ WsumT^T  (bf16 out), M=8192 N=4096 K=1024.
//     grid 512 = 32 mtiles x 16 coltiles; same-B-panel blocks on one XCD.
// ---------------------------------------------------------------------------
__global__ __launch_bounds__(512, 2) void gemm256_base(
    const bf16* __restrict__ A, const bf16* __restrict__ BT,
    bf16* __restrict__ C)
{
    __shared__ __align__(16) char smem[131072];
    const int u   = blockIdx.x;
    const int xcd = u & 7;
    const int s   = u >> 3;
    const int mt  = s & 31;
    const int ct  = xcd + 8 * (s >> 5);
    const int row0 = mt * 256, col0 = ct * 256;

    floatx4 acc[8][4];
    gemm_core256(A + (long)row0 * E_DIM, E_DIM,
                 BT + (long)col0 * E_DIM, E_DIM,
                 E_DIM, smem, acc);

    const int tid = threadIdx.x, wave = tid >> 6, lane = tid & 63;
    const int wm = wave >> 2, wn = wave & 3, fr = lane & 15, fq = lane >> 4;
    bf16* tile = (bf16*)smem;
#pragma unroll
    for (int i = 0; i < 8; ++i)
#pragma unroll
        for (int j = 0; j < 4; ++j)
#pragma unroll
            for (int r = 0; r < 4; ++r)
                tile[(wm * 128 + i * 16 + fq * 4 + r) * 256 + wn * 64 + j * 16 + fr] =
                    (bf16)(acc[i][j][r]);
    __syncthreads();
#pragma unroll
    for (int k = 0; k < 16; ++k) {
        const int rl = (tid >> 5) + k * 16;
        const int cc = (tid & 31) * 8;
        *(bf16x8*)(C + (long)(row0 + rl) * O_DIM + col0 + cc) =
            *(const bf16x8*)(tile + rl * 256 + cc);
    }
}

// ---------------------------------------------------------------------------
// 6b) sparse grouped GEMM on sorted A (256x256 tiles). Tiles may straddle an
//     expert's 128-padded boundary: straddling rows compute garbage that the
//     store mask drops. End-of-Xs slack reads land in the allocated Yb region.
//     grid 8192 = 8 experts x 64 mtiles x 16 coltiles, expert g pinned to XCD g.
// ---------------------------------------------------------------------------
__global__ __launch_bounds__(512, 2) void gemm256_sparse(
    const bf16* __restrict__ Xs,   // [padded slots][E_DIM]
    const bf16* __restrict__ WiT,  // [O_DIM][8192]
    const int* __restrict__ cnt,
    const int* __restrict__ off,
    const int* __restrict__ offp,
    const float* __restrict__ scl,
    bf16* __restrict__ ysp)        // [2*N_TOK][O_DIM] compact
{
    const int u   = blockIdx.x;
    const int xcd = u & 7;
    const int s   = u >> 3;
    const int mt  = s & 63;
    const int pc  = xcd + 8 * (s >> 6);   // [0,128)
    const int g   = pc & 7;
    const int ct  = pc >> 3;              // [0,16)

    const int cg     = cnt[g];
    const int base_p = offp[g];
    const int cgp    = offp[g + 1] - base_p;
    const int m0     = mt * 256;
    if (m0 >= cgp) return;

    __shared__ __align__(16) char smem[131072];
    const int col0 = ct * 256;

    floatx4 acc[8][4];
    gemm_core256(Xs + (long)(base_p + m0) * E_DIM, E_DIM,
                 WiT + (long)col0 * 8192 + g * E_DIM, 8192,
                 E_DIM, smem, acc);

    const int tid = threadIdx.x, wave = tid >> 6, lane = tid & 63;
    const int wm = wave >> 2, wn = wave & 3, fr = lane & 15, fq = lane >> 4;
    const float* sclg = scl + g * N_TOK;
    const int clmax = cg - 1;
    bf16* tile = (bf16*)smem;
#pragma unroll
    for (int i = 0; i < 8; ++i)
#pragma unroll
        for (int r = 0; r < 4; ++r) {
            const int rl = wm * 128 + i * 16 + fq * 4 + r;
            const int gm = m0 + rl;
            const float sv = sclg[gm > clmax ? clmax : gm];
#pragma unroll
            for (int j = 0; j < 4; ++j)
                tile[rl * 256 + wn * 64 + j * 16 + fr] = (bf16)(sv * acc[i][j][r]);
        }
    __syncthreads();
    const long ob = off[g] + m0;
#pragma unroll
    for (int k = 0; k < 16; ++k) {
        const int rl = (tid >> 5) + k * 16;
        if (m0 + rl < cg) {
            const int cc = (tid & 31) * 8;
            *(bf16x8*)(ysp + (ob + rl) * O_DIM + col0 + cc) =
                *(const bf16x8*)(tile + rl * 256 + cc);
        }
    }
}

// ---------------------------------------------------------------------------
// 6c) legacy 128x128 dense GEMM (kept for the down projection: N=1024 would
//     give only 128 blocks at 256x256).
// ---------------------------------------------------------------------------
template <typename OUT, bool VEC>
__global__ __launch_bounds__(256, 4) void gemm_mt(
    const bf16* __restrict__ A, int lda,
    const bf16* __restrict__ BT, int ldb,
    OUT* __restrict__ C, int ldc, int K)
{
    __shared__ char smem[VEC ? (128 * EPI_LD * 2) : 16384];
    bf16* As = (bf16*)smem;
    bf16* Bs = (bf16*)(smem + 8192);

    const int u   = blockIdx.x;
    const int xcd = u & 7;
    const int s   = u >> 3;
    const int mt  = s & 63;
    const int col = xcd + 8 * (s >> 6);

    const int tid  = threadIdx.x;
    const int wave = tid >> 6;
    const int lane = tid & 63;
    const int row0 = mt * 128;
    const int col0 = col * 128;

    const int sr = lane >> 2;
    const int sc = (lane & 3) * 8;
    const bf16* agp0 = A  + (long)(row0 + 16 * wave       + sr) * lda + sc;
    const bf16* agp1 = A  + (long)(row0 + 16 * (wave + 4) + sr) * lda + sc;
    const bf16* bgp0 = BT + (long)(col0 + 16 * wave       + sr) * ldb + sc;
    const bf16* bgp1 = BT + (long)(col0 + 16 * (wave + 4) + sr) * ldb + sc;
    bf16* asl0 = As + (long)wave * 512;
    bf16* asl1 = As + (long)(wave + 4) * 512;
    bf16* bsl0 = Bs + (long)wave * 512;
    bf16* bsl1 = Bs + (long)(wave + 4) * 512;

    const int mi_base = (wave >> 1) * 64;
    const int ni_base = (wave & 1) * 64;
    const int fr = lane & 15;
    const int fq = lane >> 4;

    floatx4 acc[4][4] = {};

    for (int k0 = 0; k0 < K; k0 += 32) {
        __syncthreads();
        gload_lds16(agp0 + k0, (void*)asl0);
        gload_lds16(agp1 + k0, (void*)asl1);
        gload_lds16(bgp0 + k0, (void*)bsl0);
        gload_lds16(bgp1 + k0, (void*)bsl1);
        __syncthreads();

        bf16x8 af[4], bfr[4];
#pragma unroll
        for (int i = 0; i < 4; ++i) {
            af[i]  = *(const bf16x8*)(As + (mi_base + i * 16 + fr) * 32 + fq * 8);
            bfr[i] = *(const bf16x8*)(Bs + (ni_base + i * 16 + fr) * 32 + fq * 8);
        }
#pragma unroll
        for (int i = 0; i < 4; ++i)
#pragma unroll
            for (int j = 0; j < 4; ++j)
                acc[i][j] = __builtin_amdgcn_mfma_f32_16x16x32_bf16(
                    af[i], bfr[j], acc[i][j], 0, 0, 0);
    }

    if (VEC) {
        __syncthreads();
        bf16* tile = (bf16*)smem;
#pragma unroll
        for (int i = 0; i < 4; ++i)
#pragma unroll
            for (int j = 0; j < 4; ++j)
#pragma unroll
                for (int r = 0; r < 4; ++r) {
                    const int rl = mi_base + i * 16 + fq * 4 + r;
                    const int cl = ni_base + j * 16 + fr;
                    tile[rl * EPI_LD + cl] = (bf16)acc[i][j][r];
                }
        __syncthreads();
#pragma unroll
        for (int k = 0; k < 8; ++k) {
            const int rl = (tid >> 3) + 32 * (k >> 1);
            const int cl = (tid & 7) * 8 + 64 * (k & 1);
            const bf16x8 v = *(const bf16x8*)(tile + rl * EPI_LD + cl);
            *(bf16x8*)((bf16*)C + (long)(row0 + rl) * ldc + col0 + cl) = v;
        }
    } else {
#pragma unroll
        for (int i = 0; i < 4; ++i)
#pragma unroll
            for (int j = 0; j < 4; ++j)
#pragma unroll
                for (int r = 0; r < 4; ++r) {
                    const long row = row0 + mi_base + i * 16 + fq * 4 + r;
                    const long cg  = col0 + ni_base + j * 16 + fr;
                    C[row * ldc + cg] = (OUT)acc[i][j][r];
                }
    }
}

// ---------------------------------------------------------------------------
// 8) h = bf16(relu(ybase + ysp[slot0] + ysp[slot1])^2); one block per token
// ---------------------------------------------------------------------------
__global__ __launch_bounds__(256) void relu2_gather(
    const bf16* __restrict__ Yb,   // [N_TOK][O_DIM]
    const bf16* __restrict__ ysp,  // [2*N_TOK][O_DIM]
    const int* __restrict__ pos,   // [N_TOK][2]
    const int* __restrict__ off,   // [G_DIM]
    bf16* __restrict__ H)          // [N_TOK][O_DIM]
{
    const int t  = blockIdx.x;
    const int p0 = pos[t * 2];
    const int p1 = pos[t * 2 + 1];
    const long r0 = off[p0 >> 16] + (p0 & 0xffff);
    const long r1 = off[p1 >> 16] + (p1 & 0xffff);
    const int c = threadIdx.x * 16;

    const bf16* yb = Yb + (long)t * O_DIM + c;
    const bf16* s0 = ysp + r0 * O_DIM + c;
    const bf16* s1 = ysp + r1 * O_DIM + c;
    bf16* hp = H + (long)t * O_DIM + c;

#pragma unroll
    for (int h = 0; h < 2; ++h) {
        const bf16x8 a = *(const bf16x8*)(yb + h * 8);
        const bf16x8 b = *(const bf16x8*)(s0 + h * 8);
        const bf16x8 d = *(const bf16x8*)(s1 + h * 8);
        bf16x8 o;
#pragma unroll
        for (int k = 0; k < 8; ++k) {
            float v = (float)a[k] + (float)b[k] + (float)d[k];
            v = fmaxf(v, 0.f);
            o[k] = (bf16)(v * v);
        }
        *(bf16x8*)(hp + h * 8) = o;
    }
}

// ---------------------------------------------------------------------------
extern "C" void kernel_launch(void* const* d_in, const int* in_sizes, int n_in,
                              void* d_out, int out_size, void* d_ws, size_t ws_size,
                              hipStream_t stream)
{
    const float* X  = (const float*)d_in[0];  // [4,2048,1024]
    const float* WG = (const float*)d_in[1];  // [1024,8]
    const float* Wi = (const float*)d_in[2];  // [8,1024,4096] == [8192][4096]
    const float* dn = (const float*)d_in[3];  // [4096,1024]
    float* out = (float*)d_out;               // [8192][1024] fp32

    char* ws = (char*)d_ws;
    const long MB = 1l << 20;
    int*   cnt   = (int*)ws;                        // 32 B
    int*   off   = (int*)(ws + 1024);               // 32 B
    int*   offp  = (int*)(ws + 2048);               // 36 B
    int*   pos   = (int*)(ws + 4096);               // 64 KB
    int*   tok   = (int*)(ws + 128 * 1024);         // 256 KB
    float* scl   = (float*)(ws + 448 * 1024);       // 256 KB
    int*   sel   = (int*)(ws + 704 * 1024);         // 64 KB
    float* sval  = (float*)(ws + 768 * 1024);       // 64 KB
    bf16*  dnT   = (bf16*)(ws + 1 * MB);            // 8 MB
    bf16*  WiT   = (bf16*)(ws + 9 * MB);            // 64 MB
    bf16*  Hh    = (bf16*)(ws + 9 * MB);            // 64 MB (aliases WiT; dead by then)
    bf16*  Xs    = (bf16*)(ws + 73 * MB);           // 34 MB (17408 slots; 256-row
                                                    //  tile slack reads spill into Yb)
    bf16*  Yb    = (bf16*)(ws + 107 * MB);          // 64 MB
    bf16*  ysp   = (bf16*)(ws + 171 * MB);          // 128 MB -> 299 MB high water
    bf16*  Xb    = (bf16*)(ws + 171 * MB);          // 16 MB (overlaid by ysp AFTER gather)
    bf16*  WsumT = (bf16*)(ws + 187 * MB);          // 8 MB  (overlaid by ysp after base gemm)

    gate_compute<<<dim3(N_TOK / 4), dim3(256), 0, stream>>>(X, WG, sel, sval);
    route_kernel<<<dim3(1), dim3(1024), 0, stream>>>(sel, sval, cnt, off, offp,
                                                     tok, scl, pos);
    convert_x<<<dim3(N_TOK * E_DIM / 1024), dim3(256), 0, stream>>>(X, Xb);
    transpose_conv<<<dim3(8192 / 64, O_DIM / 64), dim3(256), 0, stream>>>(Wi, WiT, 8192, O_DIM);
    transpose_conv<<<dim3(O_DIM / 64, E_DIM / 64), dim3(256), 0, stream>>>(dn, dnT, O_DIM, E_DIM);
    wsum_kernel<<<dim3(O_DIM), dim3(256), 0, stream>>>(WiT, WsumT);
    // y_base = Xb @ WsumT^T  (bf16 out); 32 mtiles x 16 coltiles, 256^2 core
    gemm256_base<<<dim3(512), dim3(512), 0, stream>>>(Xb, WsumT, Yb);
    // expert-sorted padded copy of X (after base gemm: Xb/WsumT then dead)
    gather_rows<<<dim3(17408), dim3(128), 0, stream>>>(Xb, cnt, offp, tok, Xs);
    // slot partials: scale * sortedX @ Wi[g]  (ysp overlays Xb/WsumT)
    gemm256_sparse<<<dim3(8192), dim3(512), 0, stream>>>(
        Xs, WiT, cnt, off, offp, scl, ysp);
    relu2_gather<<<dim3(N_TOK), dim3(256), 0, stream>>>(Yb, ysp, pos, off, Hh);
    // out = Hh @ dnT^T  (fp32 out); 64 mtiles x 8 coltiles (legacy 128^2)
    gemm_mt<float, false><<<dim3(64 * 8), dim3(256), 0, stream>>>(
        Hh, O_DIM, dnT, O_DIM, out, E_DIM, O_DIM);
}